// Round 9
// baseline (388.555 us; speedup 1.0000x reference)
//
#include <hip/hip_runtime.h>

#define HDIM 128
#define NGRAPH 64
#define NCLASS 7
#define PG_NODES 192  // nodes per k_pgemm block (3 sub-chunks of 64)

// ---------------- count in-degree (+edge rank) + (fused) W2 transpose ----------------
// rank[e] = this edge's arrival index among edges sharing dst -> k_edge needs no cursor.

__global__ void k_countw(const int* __restrict__ col, int E, int* __restrict__ deg,
                         int* __restrict__ rank, const float* __restrict__ W,
                         float* __restrict__ WT, int cB) {
  int b = blockIdx.x;
  if (b < cB) {
    int e = b * 256 + threadIdx.x;
    if (e < E) rank[e] = atomicAdd(&deg[col[e]], 1);
  } else {
    int idx = (b - cB) * 256 + threadIdx.x;  // 0..16383
    int c = idx >> 7, k = idx & 127;
    WT[idx] = W[k * 128 + c];
  }
}

// exclusive scan of deg (tile-local) -> packed node metadata:
//   od[i] = { off_local | batch[i]<<24 , dinv_bits }   (c-side: one 8B random load)
//   dx[i] = { dinv , x }                               (r-side: one 8B random load)
// off_local < E+N < 2^24 ok; batch < 64 (6 bits).
__global__ void k_scan1(const int* __restrict__ in, int n, const int* __restrict__ batch,
                        const float* __restrict__ x, int2* __restrict__ od,
                        float2* __restrict__ dx, int* __restrict__ tileSums) {
  __shared__ int sh[256];
  int t = threadIdx.x;
  int base = blockIdx.x * 1024 + t * 4;
  int v[4], dg[4], sum = 0;
#pragma unroll
  for (int j = 0; j < 4; j++) {
    int idx = base + j;
    int d = (idx < n) ? in[idx] : 0;
    dg[j] = d;
    v[j] = sum; sum += d;
  }
  sh[t] = sum; __syncthreads();
  for (int o = 1; o < 256; o <<= 1) {
    int val = (t >= o) ? sh[t - o] : 0;
    __syncthreads();
    sh[t] += val;
    __syncthreads();
  }
  int excl = (t == 0) ? 0 : sh[t - 1];
  if (t == 255) tileSums[blockIdx.x] = sh[255];
#pragma unroll
  for (int j = 0; j < 4; j++) {
    int idx = base + j;
    if (idx < n) {
      float dinv = rsqrtf((float)(dg[j] + 1));  // +1 self-loop
      od[idx] = make_int2((excl + v[j]) | (batch[idx] << 24), __float_as_int(dinv));
      dx[idx] = make_float2(dinv, x[idx]);
    }
  }
}

__global__ void k_scan2(int* __restrict__ tileSums, int numTiles) {
  __shared__ int sh[128];
  int t = threadIdx.x;
  sh[t] = (t < numTiles) ? tileSums[t] : 0;
  __syncthreads();
  for (int o = 1; o < 128; o <<= 1) {
    int val = (t >= o) ? sh[t - o] : 0;
    __syncthreads();
    sh[t] += val;
    __syncthreads();
  }
  if (t < numTiles) tileSums[t] = (t == 0) ? 0 : sh[t - 1];
}

// ---------------- edge pass: CSR fill (rank-based) + layer-1 scalar agg ----------------
// 2 random loads (od[c], dx[r]) + 1 scatter (gw) + 1 RMW (s[c]) per edge.
// gw.x packs src | graph<<20 so the P pass never touches row/col/batch/dinv again.

__global__ void k_edge(const int* __restrict__ row, const int* __restrict__ col,
                       const int* __restrict__ rank, int E,
                       const int2* __restrict__ od, const int* __restrict__ ts,
                       const float2* __restrict__ dx,
                       float* __restrict__ s, int2* __restrict__ gw, int n) {
  int e = blockIdx.x * blockDim.x + threadIdx.x;
  if (e < E) {
    int r = row[e], c = col[e];
    int2 oc = od[c];
    float2 dr = dx[r];
    float w = dr.x * __int_as_float(oc.y);
    int g = ((unsigned)oc.x) >> 24;
    int pos = (oc.x & 0xFFFFFF) + ts[c >> 10] + rank[e];
    gw[pos] = make_int2(r | (g << 20), __float_as_int(w));
    unsafeAtomicAdd(&s[c], w * dr.y);
  } else if (e - E < n) {
    int i = e - E;
    float2 di = dx[i];
    unsafeAtomicAdd(&s[i], di.x * di.x * di.y);  // self-loop term
  }
}

// ---------------- P build: sequential gw stream + one atomic ----------------

__global__ void k_pstream(const int2* __restrict__ gw, int E, const int2* __restrict__ od,
                          const float2* __restrict__ dx, float* __restrict__ P, int n) {
  int e = blockIdx.x * blockDim.x + threadIdx.x;
  if (e < E) {
    int2 p = gw[e];
    int r = p.x & 0xFFFFF;
    int g = ((unsigned)p.x) >> 20;
    unsafeAtomicAdd(&P[(size_t)r * NGRAPH + g], __int_as_float(p.y));
  } else if (e - E < n) {
    int i = e - E;
    float d = dx[i].x;
    int g = ((unsigned)od[i].x) >> 24;
    unsafeAtomicAdd(&P[(size_t)i * NGRAPH + g], d * d);  // self-loop coef
  }
}

// ---------------- fused: h1 = relu(s*W1+b1) recomputed per edge + agg2 ----------------

__global__ void __launch_bounds__(256) k_l2in(const float* __restrict__ s,
                                              const int2* __restrict__ od,
                                              const int* __restrict__ ts,
                                              const int2* __restrict__ gw,
                                              const float* __restrict__ W1,
                                              const float* __restrict__ b1,
                                              float2* __restrict__ z, int n, int E) {
  int node = blockIdx.x * 4 + (threadIdx.x >> 6);
  if (node >= n) return;
  int l = threadIdx.x & 63;
  float2 w1 = ((const float2*)W1)[l];
  float2 bv = ((const float2*)b1)[l];
  int2 on = od[node];
  float di = __int_as_float(on.y);
  float nself = di * di;
  float sv = s[node];
  float2 acc;
  acc.x = nself * fmaxf(fmaf(sv, w1.x, bv.x), 0.f);
  acc.y = nself * fmaxf(fmaf(sv, w1.y, bv.y), 0.f);
  int e0 = (on.x & 0xFFFFFF) + ts[node >> 10];
  int e1 = (node + 1 < n) ? ((od[node + 1].x & 0xFFFFFF) + ts[(node + 1) >> 10]) : E;
  int e = e0;
  for (; e + 4 <= e1; e += 4) {
    int2 p0 = gw[e], p1 = gw[e + 1], p2 = gw[e + 2], p3 = gw[e + 3];
    float s0 = s[p0.x & 0xFFFFF], s1 = s[p1.x & 0xFFFFF];
    float s2 = s[p2.x & 0xFFFFF], s3 = s[p3.x & 0xFFFFF];
    float u0 = __int_as_float(p0.y), u1 = __int_as_float(p1.y);
    float u2 = __int_as_float(p2.y), u3 = __int_as_float(p3.y);
    acc.x = fmaf(u0, fmaxf(fmaf(s0, w1.x, bv.x), 0.f), acc.x);
    acc.y = fmaf(u0, fmaxf(fmaf(s0, w1.y, bv.y), 0.f), acc.y);
    acc.x = fmaf(u1, fmaxf(fmaf(s1, w1.x, bv.x), 0.f), acc.x);
    acc.y = fmaf(u1, fmaxf(fmaf(s1, w1.y, bv.y), 0.f), acc.y);
    acc.x = fmaf(u2, fmaxf(fmaf(s2, w1.x, bv.x), 0.f), acc.x);
    acc.y = fmaf(u2, fmaxf(fmaf(s2, w1.y, bv.y), 0.f), acc.y);
    acc.x = fmaf(u3, fmaxf(fmaf(s3, w1.x, bv.x), 0.f), acc.x);
    acc.y = fmaf(u3, fmaxf(fmaf(s3, w1.y, bv.y), 0.f), acc.y);
  }
  for (; e < e1; e++) {
    int2 p = gw[e];
    float ss = s[p.x & 0xFFFFF];
    float w = __int_as_float(p.y);
    acc.x = fmaf(w, fmaxf(fmaf(ss, w1.x, bv.x), 0.f), acc.x);
    acc.y = fmaf(w, fmaxf(fmaf(ss, w1.y, bv.y), 0.f), acc.y);
  }
  z[(size_t)node * 64 + l] = acc;
}

// ---------------- GEMM: (n x 128) @ (128 x 128) + bias + relu ----------------
// EXACT R5 structure (75us, VGPR 68, no spill). Do NOT add register prefetch
// at launch_bounds(256,3): R6 showed it spills to scratch (1 GB HBM traffic).

__global__ void __launch_bounds__(256, 3)
k_gemm(const float* __restrict__ A, const float* __restrict__ WT,
       const float* __restrict__ bias, float* __restrict__ out, int n) {
  __shared__ float4 As4[128 * 8];  // 16 KB
  __shared__ float4 Wt4[128 * 8];  // 16 KB
  const int t = threadIdx.x;
  const int tr = t >> 4;   // 0..15 row group (8 rows each)
  const int tc = t & 15;   // 0..15 col group (8 cols each)
  const int sa = tr & 7;
  const int sw = tc & 7;
  const int rowBase = blockIdx.x << 7;

  float acc[8][8] = {};

  for (int ch = 0; ch < 4; ch++) {
    const int kOff = ch << 5;
    __syncthreads();
    for (int l = t; l < 1024; l += 256) {
      int r = l >> 3, kq = l & 7;
      int grow = rowBase + r;
      float4 v = (grow < n) ? *(const float4*)&A[(size_t)grow * 128 + kOff + (kq << 2)]
                            : make_float4(0.f, 0.f, 0.f, 0.f);
      As4[(r << 3) + (kq ^ ((r >> 3) & 7))] = v;
    }
    for (int l = t; l < 1024; l += 256) {
      int c = l >> 3, kq = l & 7;
      float4 v = *(const float4*)&WT[(size_t)c * 128 + kOff + (kq << 2)];
      Wt4[(c << 3) + (kq ^ ((c >> 3) & 7))] = v;
    }
    __syncthreads();

    for (int kq = 0; kq < 8; kq++) {
      const int ka = kq ^ sa;
      const int kw = kq ^ sw;
      float4 a[8];
#pragma unroll
      for (int i = 0; i < 8; i++) a[i] = As4[(tr << 6) + (i << 3) + ka];
#pragma unroll
      for (int j = 0; j < 8; j++) {
        float4 w = Wt4[(tc << 6) + (j << 3) + kw];
#pragma unroll
        for (int i = 0; i < 8; i++) {
          float v = acc[i][j];
          v = fmaf(a[i].x, w.x, v);
          v = fmaf(a[i].y, w.y, v);
          v = fmaf(a[i].z, w.z, v);
          v = fmaf(a[i].w, w.w, v);
          acc[i][j] = v;
        }
      }
    }
  }

  const float4 b0 = *(const float4*)&bias[(tc << 3)];
  const float4 b1v = *(const float4*)&bias[(tc << 3) + 4];
#pragma unroll
  for (int i = 0; i < 8; i++) {
    int grow = rowBase + (tr << 3) + i;
    if (grow < n) {
      float4 o0, o1;
      o0.x = fmaxf(acc[i][0] + b0.x, 0.f);
      o0.y = fmaxf(acc[i][1] + b0.y, 0.f);
      o0.z = fmaxf(acc[i][2] + b0.z, 0.f);
      o0.w = fmaxf(acc[i][3] + b0.w, 0.f);
      o1.x = fmaxf(acc[i][4] + b1v.x, 0.f);
      o1.y = fmaxf(acc[i][5] + b1v.y, 0.f);
      o1.z = fmaxf(acc[i][6] + b1v.z, 0.f);
      o1.w = fmaxf(acc[i][7] + b1v.w, 0.f);
      *(float4*)&out[(size_t)grow * 128 + (tc << 3)] = o0;
      *(float4*)&out[(size_t)grow * 128 + (tc << 3) + 4] = o1;
    }
  }
}

// ---------------- layer 3 + pool: partials[b] = P_b^T * H_b ----------------

__global__ void __launch_bounds__(256) k_pgemm(const float* __restrict__ H,
                                               const float* __restrict__ P,
                                               float* __restrict__ partials, int n) {
  __shared__ float4 Hl4[64 * 32];  // [i][j-quad]
  __shared__ float4 Pl4[64 * 16];  // [i][g-quad]
  const int t = threadIdx.x;
  const int jl = t & 31;
  const int gq = (t >> 5) << 1;
  float4 acc[8];
#pragma unroll
  for (int i = 0; i < 8; i++) acc[i] = make_float4(0.f, 0.f, 0.f, 0.f);
  const int base0 = blockIdx.x * PG_NODES;

  for (int sub = 0; sub < PG_NODES / 64; sub++) {
    const int base = base0 + sub * 64;
    __syncthreads();
    for (int l = t; l < 2048; l += 256) {
      int i = l >> 5, q = l & 31;
      int node = base + i;
      Hl4[l] = (node < n) ? *(const float4*)&H[(size_t)node * 128 + (q << 2)]
                          : make_float4(0.f, 0.f, 0.f, 0.f);
    }
    for (int l = t; l < 1024; l += 256) {
      int i = l >> 4, q = l & 15;
      int node = base + i;
      Pl4[l] = (node < n) ? *(const float4*)&P[(size_t)node * NGRAPH + (q << 2)]
                          : make_float4(0.f, 0.f, 0.f, 0.f);
    }
    __syncthreads();

#define FMA4(A, PV) \
  A.x = fmaf(PV, hv.x, A.x); A.y = fmaf(PV, hv.y, A.y); \
  A.z = fmaf(PV, hv.z, A.z); A.w = fmaf(PV, hv.w, A.w);
#pragma unroll 4
    for (int i = 0; i < 64; i++) {
      float4 hv = Hl4[i * 32 + jl];
      float4 pa = Pl4[i * 16 + gq];
      float4 pb = Pl4[i * 16 + gq + 1];
      FMA4(acc[0], pa.x) FMA4(acc[1], pa.y) FMA4(acc[2], pa.z) FMA4(acc[3], pa.w)
      FMA4(acc[4], pb.x) FMA4(acc[5], pb.y) FMA4(acc[6], pb.z) FMA4(acc[7], pb.w)
    }
#undef FMA4
  }

  float* dst = &partials[(size_t)blockIdx.x * (NGRAPH * HDIM)];
  int gb = (t >> 5) << 3;
#pragma unroll
  for (int gi = 0; gi < 8; gi++)
    *(float4*)&dst[(gb + gi) * HDIM + (jl << 2)] = acc[gi];
}

// fused tail: pooledSum = sum partials; t1 = pooled/cnt @ W3 + b3; out = t1 @ Wl + bl
__global__ void k_mid(const float* __restrict__ partials, int nPB,
                      const int* __restrict__ batch, int n,
                      const float* __restrict__ W3, const float* __restrict__ b3,
                      const float* __restrict__ Wl, const float* __restrict__ bl,
                      float* __restrict__ out) {
  __shared__ float shp[HDIM];
  __shared__ float sh[HDIM];
  __shared__ float invSh;
  int g = blockIdx.x, j = threadIdx.x;
  if (j == 0) {
    int lo = 0, hi = n;
    while (lo < hi) { int m = (lo + hi) >> 1; if (batch[m] < g) lo = m + 1; else hi = m; }
    int a = lo;
    lo = 0; hi = n;
    while (lo < hi) { int m = (lo + hi) >> 1; if (batch[m] < g + 1) lo = m + 1; else hi = m; }
    invSh = 1.f / fmaxf((float)(lo - a), 1.f);
  }
  size_t base = (size_t)g * HDIM + j;
  float a0 = 0.f, a1 = 0.f, a2 = 0.f, a3 = 0.f;
  int p = 0;
  for (; p + 4 <= nPB; p += 4) {
    a0 += partials[(size_t)(p + 0) * (NGRAPH * HDIM) + base];
    a1 += partials[(size_t)(p + 1) * (NGRAPH * HDIM) + base];
    a2 += partials[(size_t)(p + 2) * (NGRAPH * HDIM) + base];
    a3 += partials[(size_t)(p + 3) * (NGRAPH * HDIM) + base];
  }
  for (; p < nPB; p++) a0 += partials[(size_t)p * (NGRAPH * HDIM) + base];
  shp[j] = (a0 + a1) + (a2 + a3);
  __syncthreads();
  float inv = invSh;
  float acc = 0.f;
  for (int k = 0; k < HDIM; k++) acc = fmaf(shp[k], W3[k * HDIM + j], acc);
  sh[j] = acc * inv + b3[j];
  __syncthreads();
  if (j < NCLASS) {
    float o = bl[j];
    for (int k = 0; k < HDIM; k++) o = fmaf(sh[k], Wl[k * NCLASS + j], o);
    out[g * NCLASS + j] = o;
  }
}

// ---------------- host ----------------

extern "C" void kernel_launch(void* const* d_in, const int* in_sizes, int n_in,
                              void* d_out, int out_size, void* d_ws, size_t ws_size,
                              hipStream_t stream) {
  const float* x   = (const float*)d_in[0];
  const int*   ei  = (const int*)d_in[1];
  const int*   bat = (const int*)d_in[2];
  const float* W1  = (const float*)d_in[3];
  const float* b1  = (const float*)d_in[4];
  const float* W2  = (const float*)d_in[5];
  const float* b2  = (const float*)d_in[6];
  const float* W3  = (const float*)d_in[7];
  const float* b3  = (const float*)d_in[8];
  const float* Wl  = (const float*)d_in[9];
  const float* bl  = (const float*)d_in[10];
  float* out = (float*)d_out;

  const int n = in_sizes[0];
  const int E = in_sizes[1] / 2;
  const int* rowv = ei;            // edge_index[0] : message source
  const int* colv = ei + E;        // edge_index[1] : aggregation destination

  char* w = (char*)d_ws;
  size_t o = 0;
  auto alloc = [&](size_t bytes) {
    size_t r = (o + 255) & ~(size_t)255;
    o = r + bytes;
    return r;
  };
  const int nPB = (n + PG_NODES - 1) / PG_NODES;

  // Path A layout: standalone P + partials; single upfront memset (deg, s, P).
  size_t o_deg  = alloc((size_t)n * 4);
  size_t o_s    = alloc((size_t)n * 4);
  size_t o_P    = alloc((size_t)n * NGRAPH * 4);  // 25.6 MB
  size_t zero_end = o;
  size_t o_ts   = alloc(256 * 4);
  size_t o_od   = alloc((size_t)n * 8);
  size_t o_dx   = alloc((size_t)n * 8);
  size_t o_rank = alloc((size_t)E * 4);
  size_t o_wt   = alloc((size_t)HDIM * HDIM * 4);
  size_t o_gw   = alloc((size_t)E * 8);
  size_t o_bufA = alloc((size_t)n * HDIM * 4);
  size_t o_bufB = alloc((size_t)n * HDIM * 4);
  size_t o_part = alloc((size_t)nPB * NGRAPH * HDIM * 4);  // ~17 MB
  const bool fitsA = (o <= ws_size);
  (void)n_in; (void)out_size;

  if (!fitsA) {
    // Path B: P + partials alias bufB (dead after gemm); separate memset for P.
    o = 0;
    o_deg  = alloc((size_t)n * 4);
    o_s    = alloc((size_t)n * 4);
    zero_end = o;
    o_ts   = alloc(256 * 4);
    o_od   = alloc((size_t)n * 8);
    o_dx   = alloc((size_t)n * 8);
    o_rank = alloc((size_t)E * 4);
    o_wt   = alloc((size_t)HDIM * HDIM * 4);
    o_gw   = alloc((size_t)E * 8);
    o_bufA = alloc((size_t)n * HDIM * 4);
    o_bufB = alloc((size_t)n * HDIM * 4);
    o_P    = o_bufB;
    o_part = o_bufB + (size_t)n * NGRAPH * 4;
  }

  int*    deg      = (int*)(w + o_deg);
  float*  s        = (float*)(w + o_s);
  int*    ts       = (int*)(w + o_ts);
  int2*   od       = (int2*)(w + o_od);
  float2* dx       = (float2*)(w + o_dx);
  int*    rank     = (int*)(w + o_rank);
  float*  W2T      = (float*)(w + o_wt);
  int2*   gw       = (int2*)(w + o_gw);
  float*  bufA     = (float*)(w + o_bufA);   // h2 (gemm out)
  float*  bufB     = (float*)(w + o_bufB);   // z (gemm in)
  float*  P        = (float*)(w + o_P);
  float*  partials = (float*)(w + o_part);

  hipMemsetAsync(w + o_deg, 0, zero_end - o_deg, stream);

  const int nTiles = (n + 1023) / 1024;
  const int cB = (E + 255) / 256;
  k_countw<<<cB + 64, 256, 0, stream>>>(colv, E, deg, rank, W2, W2T, cB);
  k_scan1<<<nTiles, 256, 0, stream>>>(deg, n, bat, x, od, dx, ts);
  k_scan2<<<1, 128, 0, stream>>>(ts, nTiles);

  // CSR fill (rank-based, packed metadata) + layer-1 scalar aggregation
  k_edge<<<(E + n + 255) / 256, 256, 0, stream>>>(rowv, colv, rank, E, od, ts, dx, s, gw, n);

  // fused rank-1 h1 + relu + layer-2 aggregation -> z (bufB)
  k_l2in<<<(n + 3) / 4, 256, 0, stream>>>(s, od, ts, gw, W1, b1, (float2*)bufB, n, E);

  // layer 2 GEMM (+bias+relu): bufB @ W2 -> bufA
  k_gemm<<<(n + 127) / 128, 256, 0, stream>>>(bufB, W2T, b2, bufA, n);

  if (!fitsA) hipMemsetAsync(P, 0, (size_t)n * NGRAPH * 4, stream);

  // P from sequential gw stream (works in both paths: bufB dead after gemm)
  k_pstream<<<(E + n + 255) / 256, 256, 0, stream>>>(gw, E, od, dx, P, n);

  // layer 3 + pool: partials = P^T * h2 per block
  k_pgemm<<<nPB, 256, 0, stream>>>(bufA, P, partials, n);

  // fused tail: partials reduce + mid GEMM + classifier
  k_mid<<<NGRAPH, HDIM, 0, stream>>>(partials, nPB, bat, n, W3, b3, Wl, bl, out);
}

// Round 10
// 357.826 us; speedup vs baseline: 1.0859x; 1.0859x over previous
//
#include <hip/hip_runtime.h>

#define HDIM 128
#define NGRAPH 64
#define NCLASS 7
#define PG_NODES 192  // nodes per k_pgemm block (3 sub-chunks of 64)

// ---------------- count in-degree (+edge rank) + (fused) W2 transpose ----------------
// rank[e] = this edge's arrival index among edges sharing dst -> k_edge needs no cursor.

__global__ void k_countw(const int* __restrict__ col, int E, int* __restrict__ deg,
                         int* __restrict__ rank, const float* __restrict__ W,
                         float* __restrict__ WT, int cB) {
  int b = blockIdx.x;
  if (b < cB) {
    int e = b * 256 + threadIdx.x;
    if (e < E) rank[e] = atomicAdd(&deg[col[e]], 1);
  } else {
    int idx = (b - cB) * 256 + threadIdx.x;  // 0..16383
    int c = idx >> 7, k = idx & 127;
    WT[idx] = W[k * 128 + c];
  }
}

// exclusive scan of deg (tile-local) -> packed node metadata:
//   od[i] = { off_local | batch[i]<<24 , dinv_bits }   (c-side: one 8B random load)
//   dx[i] = { dinv , x }                               (r-side: one 8B random load)
__global__ void k_scan1(const int* __restrict__ in, int n, const int* __restrict__ batch,
                        const float* __restrict__ x, int2* __restrict__ od,
                        float2* __restrict__ dx, int* __restrict__ tileSums) {
  __shared__ int sh[256];
  int t = threadIdx.x;
  int base = blockIdx.x * 1024 + t * 4;
  int v[4], dg[4], sum = 0;
#pragma unroll
  for (int j = 0; j < 4; j++) {
    int idx = base + j;
    int d = (idx < n) ? in[idx] : 0;
    dg[j] = d;
    v[j] = sum; sum += d;
  }
  sh[t] = sum; __syncthreads();
  for (int o = 1; o < 256; o <<= 1) {
    int val = (t >= o) ? sh[t - o] : 0;
    __syncthreads();
    sh[t] += val;
    __syncthreads();
  }
  int excl = (t == 0) ? 0 : sh[t - 1];
  if (t == 255) tileSums[blockIdx.x] = sh[255];
#pragma unroll
  for (int j = 0; j < 4; j++) {
    int idx = base + j;
    if (idx < n) {
      float dinv = rsqrtf((float)(dg[j] + 1));  // +1 self-loop
      od[idx] = make_int2((excl + v[j]) | (batch[idx] << 24), __float_as_int(dinv));
      dx[idx] = make_float2(dinv, x[idx]);
    }
  }
}

__global__ void k_scan2(int* __restrict__ tileSums, int numTiles) {
  __shared__ int sh[128];
  int t = threadIdx.x;
  sh[t] = (t < numTiles) ? tileSums[t] : 0;
  __syncthreads();
  for (int o = 1; o < 128; o <<= 1) {
    int val = (t >= o) ? sh[t - o] : 0;
    __syncthreads();
    sh[t] += val;
    __syncthreads();
  }
  if (t < numTiles) tileSums[t] = (t == 0) ? 0 : sh[t - 1];
}

// ---------------- edge pass: CSR fill + layer-1 scalar agg (+P when standalone) ----------------
// Per edge: od[c], dx[r] random loads; gw scatter; s[c] RMW; optional P[r][g] RMW.
// gw.x packs src | graph<<20 (src < 2^20, g < 64).

__global__ void k_edge(const int* __restrict__ row, const int* __restrict__ col,
                       const int* __restrict__ rank, int E,
                       const int2* __restrict__ od, const int* __restrict__ ts,
                       const float2* __restrict__ dx,
                       float* __restrict__ s, int2* __restrict__ gw,
                       float* __restrict__ P, int n) {
  int e = blockIdx.x * blockDim.x + threadIdx.x;
  if (e < E) {
    int r = row[e], c = col[e];
    int2 oc = od[c];
    float2 dr = dx[r];
    float w = dr.x * __int_as_float(oc.y);
    int g = ((unsigned)oc.x) >> 24;
    int pos = (oc.x & 0xFFFFFF) + ts[c >> 10] + rank[e];
    gw[pos] = make_int2(r | (g << 20), __float_as_int(w));
    unsafeAtomicAdd(&s[c], w * dr.y);
    if (P) unsafeAtomicAdd(&P[(size_t)r * NGRAPH + g], w);
  } else if (e - E < n) {
    int i = e - E;
    float2 di = dx[i];
    float dd = di.x * di.x;
    unsafeAtomicAdd(&s[i], dd * di.y);  // self-loop term
    if (P) {
      int g = ((unsigned)od[i].x) >> 24;
      unsafeAtomicAdd(&P[(size_t)i * NGRAPH + g], dd);
    }
  }
}

// ---------------- P build from gw stream (Path B fallback only) ----------------

__global__ void k_pstream(const int2* __restrict__ gw, int E, const int2* __restrict__ od,
                          const float2* __restrict__ dx, float* __restrict__ P, int n) {
  int e = blockIdx.x * blockDim.x + threadIdx.x;
  if (e < E) {
    int2 p = gw[e];
    int r = p.x & 0xFFFFF;
    int g = ((unsigned)p.x) >> 20;
    unsafeAtomicAdd(&P[(size_t)r * NGRAPH + g], __int_as_float(p.y));
  } else if (e - E < n) {
    int i = e - E;
    float d = dx[i].x;
    int g = ((unsigned)od[i].x) >> 24;
    unsafeAtomicAdd(&P[(size_t)i * NGRAPH + g], d * d);
  }
}

// ---------------- fused: h1 = relu(s*W1+b1) recomputed per edge + agg2 ----------------

__global__ void __launch_bounds__(256) k_l2in(const float* __restrict__ s,
                                              const int2* __restrict__ od,
                                              const int* __restrict__ ts,
                                              const int2* __restrict__ gw,
                                              const float* __restrict__ W1,
                                              const float* __restrict__ b1,
                                              float2* __restrict__ z, int n, int E) {
  int node = blockIdx.x * 4 + (threadIdx.x >> 6);
  if (node >= n) return;
  int l = threadIdx.x & 63;
  float2 w1 = ((const float2*)W1)[l];
  float2 bv = ((const float2*)b1)[l];
  int2 on = od[node];
  float di = __int_as_float(on.y);
  float nself = di * di;
  float sv = s[node];
  float2 acc;
  acc.x = nself * fmaxf(fmaf(sv, w1.x, bv.x), 0.f);
  acc.y = nself * fmaxf(fmaf(sv, w1.y, bv.y), 0.f);
  int e0 = (on.x & 0xFFFFFF) + ts[node >> 10];
  int e1 = (node + 1 < n) ? ((od[node + 1].x & 0xFFFFFF) + ts[(node + 1) >> 10]) : E;
  int e = e0;
  for (; e + 4 <= e1; e += 4) {
    int2 p0 = gw[e], p1 = gw[e + 1], p2 = gw[e + 2], p3 = gw[e + 3];
    float s0 = s[p0.x & 0xFFFFF], s1 = s[p1.x & 0xFFFFF];
    float s2 = s[p2.x & 0xFFFFF], s3 = s[p3.x & 0xFFFFF];
    float u0 = __int_as_float(p0.y), u1 = __int_as_float(p1.y);
    float u2 = __int_as_float(p2.y), u3 = __int_as_float(p3.y);
    acc.x = fmaf(u0, fmaxf(fmaf(s0, w1.x, bv.x), 0.f), acc.x);
    acc.y = fmaf(u0, fmaxf(fmaf(s0, w1.y, bv.y), 0.f), acc.y);
    acc.x = fmaf(u1, fmaxf(fmaf(s1, w1.x, bv.x), 0.f), acc.x);
    acc.y = fmaf(u1, fmaxf(fmaf(s1, w1.y, bv.y), 0.f), acc.y);
    acc.x = fmaf(u2, fmaxf(fmaf(s2, w1.x, bv.x), 0.f), acc.x);
    acc.y = fmaf(u2, fmaxf(fmaf(s2, w1.y, bv.y), 0.f), acc.y);
    acc.x = fmaf(u3, fmaxf(fmaf(s3, w1.x, bv.x), 0.f), acc.x);
    acc.y = fmaf(u3, fmaxf(fmaf(s3, w1.y, bv.y), 0.f), acc.y);
  }
  for (; e < e1; e++) {
    int2 p = gw[e];
    float ss = s[p.x & 0xFFFFF];
    float w = __int_as_float(p.y);
    acc.x = fmaf(w, fmaxf(fmaf(ss, w1.x, bv.x), 0.f), acc.x);
    acc.y = fmaf(w, fmaxf(fmaf(ss, w1.y, bv.y), 0.f), acc.y);
  }
  z[(size_t)node * 64 + l] = acc;
}

// ---------------- GEMM: (n x 128) @ (128 x 128) + bias + relu ----------------
// EXACT R5 structure (75us, VGPR 68, no spill). Do NOT add register prefetch
// at launch_bounds(256,3): R6 showed it spills to scratch (1 GB HBM traffic).

__global__ void __launch_bounds__(256, 3)
k_gemm(const float* __restrict__ A, const float* __restrict__ WT,
       const float* __restrict__ bias, float* __restrict__ out, int n) {
  __shared__ float4 As4[128 * 8];  // 16 KB
  __shared__ float4 Wt4[128 * 8];  // 16 KB
  const int t = threadIdx.x;
  const int tr = t >> 4;   // 0..15 row group (8 rows each)
  const int tc = t & 15;   // 0..15 col group (8 cols each)
  const int sa = tr & 7;
  const int sw = tc & 7;
  const int rowBase = blockIdx.x << 7;

  float acc[8][8] = {};

  for (int ch = 0; ch < 4; ch++) {
    const int kOff = ch << 5;
    __syncthreads();
    for (int l = t; l < 1024; l += 256) {
      int r = l >> 3, kq = l & 7;
      int grow = rowBase + r;
      float4 v = (grow < n) ? *(const float4*)&A[(size_t)grow * 128 + kOff + (kq << 2)]
                            : make_float4(0.f, 0.f, 0.f, 0.f);
      As4[(r << 3) + (kq ^ ((r >> 3) & 7))] = v;
    }
    for (int l = t; l < 1024; l += 256) {
      int c = l >> 3, kq = l & 7;
      float4 v = *(const float4*)&WT[(size_t)c * 128 + kOff + (kq << 2)];
      Wt4[(c << 3) + (kq ^ ((c >> 3) & 7))] = v;
    }
    __syncthreads();

    for (int kq = 0; kq < 8; kq++) {
      const int ka = kq ^ sa;
      const int kw = kq ^ sw;
      float4 a[8];
#pragma unroll
      for (int i = 0; i < 8; i++) a[i] = As4[(tr << 6) + (i << 3) + ka];
#pragma unroll
      for (int j = 0; j < 8; j++) {
        float4 w = Wt4[(tc << 6) + (j << 3) + kw];
#pragma unroll
        for (int i = 0; i < 8; i++) {
          float v = acc[i][j];
          v = fmaf(a[i].x, w.x, v);
          v = fmaf(a[i].y, w.y, v);
          v = fmaf(a[i].z, w.z, v);
          v = fmaf(a[i].w, w.w, v);
          acc[i][j] = v;
        }
      }
    }
  }

  const float4 b0 = *(const float4*)&bias[(tc << 3)];
  const float4 b1v = *(const float4*)&bias[(tc << 3) + 4];
#pragma unroll
  for (int i = 0; i < 8; i++) {
    int grow = rowBase + (tr << 3) + i;
    if (grow < n) {
      float4 o0, o1;
      o0.x = fmaxf(acc[i][0] + b0.x, 0.f);
      o0.y = fmaxf(acc[i][1] + b0.y, 0.f);
      o0.z = fmaxf(acc[i][2] + b0.z, 0.f);
      o0.w = fmaxf(acc[i][3] + b0.w, 0.f);
      o1.x = fmaxf(acc[i][4] + b1v.x, 0.f);
      o1.y = fmaxf(acc[i][5] + b1v.y, 0.f);
      o1.z = fmaxf(acc[i][6] + b1v.z, 0.f);
      o1.w = fmaxf(acc[i][7] + b1v.w, 0.f);
      *(float4*)&out[(size_t)grow * 128 + (tc << 3)] = o0;
      *(float4*)&out[(size_t)grow * 128 + (tc << 3) + 4] = o1;
    }
  }
}

// ---------------- layer 3 + pool: partials[b] = P_b^T * H_b ----------------

__global__ void __launch_bounds__(256) k_pgemm(const float* __restrict__ H,
                                               const float* __restrict__ P,
                                               float* __restrict__ partials, int n) {
  __shared__ float4 Hl4[64 * 32];  // [i][j-quad]
  __shared__ float4 Pl4[64 * 16];  // [i][g-quad]
  const int t = threadIdx.x;
  const int jl = t & 31;
  const int gq = (t >> 5) << 1;
  float4 acc[8];
#pragma unroll
  for (int i = 0; i < 8; i++) acc[i] = make_float4(0.f, 0.f, 0.f, 0.f);
  const int base0 = blockIdx.x * PG_NODES;

  for (int sub = 0; sub < PG_NODES / 64; sub++) {
    const int base = base0 + sub * 64;
    __syncthreads();
    for (int l = t; l < 2048; l += 256) {
      int i = l >> 5, q = l & 31;
      int node = base + i;
      Hl4[l] = (node < n) ? *(const float4*)&H[(size_t)node * 128 + (q << 2)]
                          : make_float4(0.f, 0.f, 0.f, 0.f);
    }
    for (int l = t; l < 1024; l += 256) {
      int i = l >> 4, q = l & 15;
      int node = base + i;
      Pl4[l] = (node < n) ? *(const float4*)&P[(size_t)node * NGRAPH + (q << 2)]
                          : make_float4(0.f, 0.f, 0.f, 0.f);
    }
    __syncthreads();

#define FMA4(A, PV) \
  A.x = fmaf(PV, hv.x, A.x); A.y = fmaf(PV, hv.y, A.y); \
  A.z = fmaf(PV, hv.z, A.z); A.w = fmaf(PV, hv.w, A.w);
#pragma unroll 4
    for (int i = 0; i < 64; i++) {
      float4 hv = Hl4[i * 32 + jl];
      float4 pa = Pl4[i * 16 + gq];
      float4 pb = Pl4[i * 16 + gq + 1];
      FMA4(acc[0], pa.x) FMA4(acc[1], pa.y) FMA4(acc[2], pa.z) FMA4(acc[3], pa.w)
      FMA4(acc[4], pb.x) FMA4(acc[5], pb.y) FMA4(acc[6], pb.z) FMA4(acc[7], pb.w)
    }
#undef FMA4
  }

  float* dst = &partials[(size_t)blockIdx.x * (NGRAPH * HDIM)];
  int gb = (t >> 5) << 3;
#pragma unroll
  for (int gi = 0; gi < 8; gi++)
    *(float4*)&dst[(gb + gi) * HDIM + (jl << 2)] = acc[gi];
}

// parallel partials reduce (R8-proven): grid (32, 8), block 256
__global__ void k_reduce(const float* __restrict__ partials, float* __restrict__ pooled,
                         int nparts) {
  int cell = blockIdx.x * 256 + threadIdx.x;
  int stride = gridDim.y;
  int p = blockIdx.y;
  float a0 = 0.f, a1 = 0.f, a2 = 0.f, a3 = 0.f;
  for (; p + 3 * stride < nparts; p += 4 * stride) {
    a0 += partials[(size_t)p * 8192 + cell];
    a1 += partials[(size_t)(p + stride) * 8192 + cell];
    a2 += partials[(size_t)(p + 2 * stride) * 8192 + cell];
    a3 += partials[(size_t)(p + 3 * stride) * 8192 + cell];
  }
  for (; p < nparts; p += stride) a0 += partials[(size_t)p * 8192 + cell];
  unsafeAtomicAdd(&pooled[cell], (a0 + a1) + (a2 + a3));
}

// fused tail: t1 = pooled/cnt @ W3 + b3 (in LDS), then out = t1 @ Wl + bl
__global__ void k_mid(const float* __restrict__ pooled, const int* __restrict__ batch, int n,
                      const float* __restrict__ W3, const float* __restrict__ b3,
                      const float* __restrict__ Wl, const float* __restrict__ bl,
                      float* __restrict__ out) {
  __shared__ float sh[HDIM];
  __shared__ float invSh;
  int g = blockIdx.x, j = threadIdx.x;
  if (j == 0) {
    int lo = 0, hi = n;
    while (lo < hi) { int m = (lo + hi) >> 1; if (batch[m] < g) lo = m + 1; else hi = m; }
    int a = lo;
    lo = 0; hi = n;
    while (lo < hi) { int m = (lo + hi) >> 1; if (batch[m] < g + 1) lo = m + 1; else hi = m; }
    invSh = 1.f / fmaxf((float)(lo - a), 1.f);
  }
  __syncthreads();
  float inv = invSh;
  float acc = 0.f;
  for (int k = 0; k < HDIM; k++) acc = fmaf(pooled[g * HDIM + k], W3[k * HDIM + j], acc);
  sh[j] = acc * inv + b3[j];
  __syncthreads();
  if (j < NCLASS) {
    float o = bl[j];
    for (int k = 0; k < HDIM; k++) o = fmaf(sh[k], Wl[k * NCLASS + j], o);
    out[g * NCLASS + j] = o;
  }
}

// ---------------- host ----------------

extern "C" void kernel_launch(void* const* d_in, const int* in_sizes, int n_in,
                              void* d_out, int out_size, void* d_ws, size_t ws_size,
                              hipStream_t stream) {
  const float* x   = (const float*)d_in[0];
  const int*   ei  = (const int*)d_in[1];
  const int*   bat = (const int*)d_in[2];
  const float* W1  = (const float*)d_in[3];
  const float* b1  = (const float*)d_in[4];
  const float* W2  = (const float*)d_in[5];
  const float* b2  = (const float*)d_in[6];
  const float* W3  = (const float*)d_in[7];
  const float* b3  = (const float*)d_in[8];
  const float* Wl  = (const float*)d_in[9];
  const float* bl  = (const float*)d_in[10];
  float* out = (float*)d_out;

  const int n = in_sizes[0];
  const int E = in_sizes[1] / 2;
  const int* rowv = ei;            // edge_index[0] : message source
  const int* colv = ei + E;        // edge_index[1] : aggregation destination

  char* w = (char*)d_ws;
  size_t o = 0;
  auto alloc = [&](size_t bytes) {
    size_t r = (o + 255) & ~(size_t)255;
    o = r + bytes;
    return r;
  };
  const int nPB = (n + PG_NODES - 1) / PG_NODES;

  // Path A layout: standalone P + partials; single upfront memset (deg, s, pooled, P).
  size_t o_deg  = alloc((size_t)n * 4);
  size_t o_s    = alloc((size_t)n * 4);
  size_t o_pool = alloc((size_t)NGRAPH * HDIM * 4);
  size_t o_P    = alloc((size_t)n * NGRAPH * 4);  // 25.6 MB
  size_t zero_end = o;
  size_t o_ts   = alloc(256 * 4);
  size_t o_od   = alloc((size_t)n * 8);
  size_t o_dx   = alloc((size_t)n * 8);
  size_t o_rank = alloc((size_t)E * 4);
  size_t o_wt   = alloc((size_t)HDIM * HDIM * 4);
  size_t o_gw   = alloc((size_t)E * 8);
  size_t o_bufA = alloc((size_t)n * HDIM * 4);
  size_t o_bufB = alloc((size_t)n * HDIM * 4);
  size_t o_part = alloc((size_t)nPB * NGRAPH * HDIM * 4);  // ~17 MB
  const bool fitsA = (o <= ws_size);
  (void)n_in; (void)out_size;

  if (!fitsA) {
    // Path B: P + partials alias bufB (dead after gemm); separate memset for P.
    o = 0;
    o_deg  = alloc((size_t)n * 4);
    o_s    = alloc((size_t)n * 4);
    o_pool = alloc((size_t)NGRAPH * HDIM * 4);
    zero_end = o;
    o_ts   = alloc(256 * 4);
    o_od   = alloc((size_t)n * 8);
    o_dx   = alloc((size_t)n * 8);
    o_rank = alloc((size_t)E * 4);
    o_wt   = alloc((size_t)HDIM * HDIM * 4);
    o_gw   = alloc((size_t)E * 8);
    o_bufA = alloc((size_t)n * HDIM * 4);
    o_bufB = alloc((size_t)n * HDIM * 4);
    o_P    = o_bufB;
    o_part = o_bufB + (size_t)n * NGRAPH * 4;
  }

  int*    deg      = (int*)(w + o_deg);
  float*  s        = (float*)(w + o_s);
  float*  pooled   = (float*)(w + o_pool);
  int*    ts       = (int*)(w + o_ts);
  int2*   od       = (int2*)(w + o_od);
  float2* dx       = (float2*)(w + o_dx);
  int*    rank     = (int*)(w + o_rank);
  float*  W2T      = (float*)(w + o_wt);
  int2*   gw       = (int2*)(w + o_gw);
  float*  bufA     = (float*)(w + o_bufA);   // h2 (gemm out)
  float*  bufB     = (float*)(w + o_bufB);   // z (gemm in)
  float*  P        = (float*)(w + o_P);
  float*  partials = (float*)(w + o_part);

  hipMemsetAsync(w + o_deg, 0, zero_end - o_deg, stream);

  const int nTiles = (n + 1023) / 1024;
  const int cB = (E + 255) / 256;
  k_countw<<<cB + 64, 256, 0, stream>>>(colv, E, deg, rank, W2, W2T, cB);
  k_scan1<<<nTiles, 256, 0, stream>>>(deg, n, bat, x, od, dx, ts);
  k_scan2<<<1, 128, 0, stream>>>(ts, nTiles);

  // CSR fill + layer-1 scalar aggregation (+ P accumulation in Path A)
  k_edge<<<(E + n + 255) / 256, 256, 0, stream>>>(rowv, colv, rank, E, od, ts, dx, s, gw,
                                                  fitsA ? P : nullptr, n);

  // fused rank-1 h1 + relu + layer-2 aggregation -> z (bufB)
  k_l2in<<<(n + 3) / 4, 256, 0, stream>>>(s, od, ts, gw, W1, b1, (float2*)bufB, n, E);

  // layer 2 GEMM (+bias+relu): bufB @ W2 -> bufA
  k_gemm<<<(n + 127) / 128, 256, 0, stream>>>(bufB, W2T, b2, bufA, n);

  if (!fitsA) {
    hipMemsetAsync(P, 0, (size_t)n * NGRAPH * 4, stream);
    k_pstream<<<(E + n + 255) / 256, 256, 0, stream>>>(gw, E, od, dx, P, n);
  }

  // layer 3 + pool: partials = P^T * h2 per block, then parallel reduce
  k_pgemm<<<nPB, 256, 0, stream>>>(bufA, P, partials, n);
  k_reduce<<<dim3(32, 8), 256, 0, stream>>>(partials, pooled, nPB);

  // fused tail: mid GEMM + classifier
  k_mid<<<NGRAPH, HDIM, 0, stream>>>(pooled, bat, n, W3, b3, Wl, bl, out);
}